// Round 12
// baseline (860.252 us; speedup 1.0000x reference)
//
#include <hip/hip_runtime.h>
#include <cmath>

static constexpr int Bn = 128;
static constexpr int Nn = 256;
static constexpr int META_PB = 131072;   // per-batch metadata bytes (uint8)

// ---------------------------------------------------------------------------
// Kernel 1: z = logits - log(-log(clip(u))), zero arb, init score matrix
// M[b][i][j] (stride 256) with diag & column-0 = -inf.
// ---------------------------------------------------------------------------
template <typename T>
__global__ __launch_bounds__(256) void zinit_kernel(
    const float* __restrict__ logits,
    const float* __restrict__ u,
    float* __restrict__ zout,
    float* __restrict__ arb,
    T* __restrict__ M)
{
    int idx = blockIdx.x * blockDim.x + threadIdx.x;   // < Bn*Nn*Nn
    int j = idx & (Nn - 1);
    int i = (idx >> 8) & (Nn - 1);
    const float EPS = 1.1920928955078125e-07f;         // float32 eps
    float uv = u[idx];
    uv = fminf(fmaxf(uv, EPS), 1.0f - EPS);
    float z = logits[idx] - logf(-logf(uv));
    zout[idx] = z;
    arb[idx] = 0.0f;
    M[idx] = (i == j || j == 0) ? (T)(-INFINITY) : (T)z;
}

// ---------------------------------------------------------------------------
// Kernel 2: per-batch Chu-Liu/Edmonds with SIMULTANEOUS contraction of all
// disjoint argmax-graph cycles per level (order-invariant for generic
// weights => identical unique optimum, ~2.5x fewer levels). 256 threads.
// In-place supernode rows/cols, incremental argmax (alive-head keep),
// R10-style batched gathers and rescans.
// Meta stream per level: [non n][mem tm][memhead tm][argout ncyc*Lc][argin ncyc*n_new]
// ---------------------------------------------------------------------------
template <typename T>
__global__ __launch_bounds__(256) void edmonds_kernel(
    const int* __restrict__ lengths,
    const float* __restrict__ zout,
    T* __restrict__ Mg,
    unsigned char* __restrict__ metag,
    float* __restrict__ arb,
    float* __restrict__ stats)
{
    const int b = blockIdx.x;
    const int t = threadIdx.x;
    const int lane = t & 63, wv = t >> 6;
    T* M = Mg + (size_t)b * (Nn * Nn);
    unsigned char* mp = metag + (size_t)b * META_PB;
    const float* zb = zout + (size_t)b * (Nn * Nn);

    __shared__ unsigned short act[256];      // compact index -> original slot
    __shared__ unsigned short h[256];        // compact heads
    __shared__ unsigned short h2[256];       // unwind ping-pong
    __shared__ unsigned short p1[256];       // pointer doubling A
    __shared__ unsigned short p2[256];       // pointer doubling B
    __shared__ unsigned short inv_[256];     // old compact -> new compact (survivors)
    __shared__ unsigned short cycnodes[256]; // cyclic nodes (sorted)
    __shared__ unsigned short cmem[256];     // member stream (old idx)
    __shared__ unsigned short cmemhead[256]; // member heads (old idx)
    __shared__ unsigned short non_c[256];
    __shared__ unsigned short resc[256];
    __shared__ unsigned short coff[130];     // per-cycle offsets into stream
    __shared__ unsigned short wsl[129];      // per-cycle representative slot
    __shared__ unsigned short lev_n[256], lev_ncyc[256], lev_Lc[256];
    __shared__ int lev_off[256];
    __shared__ unsigned char in_cyc[256];    // cyclic-node mark
    __shared__ unsigned char cid[256];       // member -> cycle id (0xFF none)
    __shared__ T hval[256];                  // per-column current max
    __shared__ T chsm[256];                  // chs per member stream pos
    __shared__ double red[256];
    __shared__ int wcntC[4], wcntS[4];
    __shared__ int sh_ncyc, sh_cnt;

    const int L = lengths[b];

    act[t] = (unsigned short)t;
    // ---- initial full column argmax (first-max), 8-wide load batching ----
    if (t < L) {
        T best = -INFINITY; int bi = 0;
        const T* col = M + t;
        int i = 0;
        for (; i + 8 <= L; i += 8) {
            T v[8];
            #pragma unroll
            for (int k = 0; k < 8; ++k) v[k] = col[(i + k) * Nn];
            #pragma unroll
            for (int k = 0; k < 8; ++k)
                if (v[k] > best) { best = v[k]; bi = i + k; }
        }
        for (; i < L; ++i) {
            T v = col[i * Nn];
            if (v > best) { best = v; bi = i; }
        }
        h[t] = (t == 0) ? (unsigned short)0 : (unsigned short)bi;
        hval[t] = best;
    }
    __syncthreads();

    int Lc = L, depth = 0, moff = 0;

    while (true) {
        // ---- A: clear marks/ids, seed doubling ----
        in_cyc[t] = 0;
        cid[t] = 0xFF;
        if (t < Lc) p1[t] = h[t];
        __syncthreads();

        // ---- pointer doubling (ping-pong, 1 barrier/round) ----
        const int rounds = 32 - __clz(Lc - 1);       // ceil(log2(Lc)), Lc>=2
        unsigned short* pa = p1;
        unsigned short* pb = p2;
        for (int r = 0; r < rounds; ++r) {
            if (t < Lc) pb[t] = pa[pa[t]];
            __syncthreads();
            unsigned short* tmp = pa; pa = pb; pb = tmp;
        }

        // ---- mark ALL cyclic nodes: p[t] lands on a (non-root) cycle ----
        if (t < Lc && pa[t] != 0) in_cyc[pa[t]] = 1;
        __syncthreads();

        // ---- ballot compaction: cyclic list + survivor list ----
        const bool isC = (t < Lc) && in_cyc[t];
        const bool isS = (t < Lc) && !in_cyc[t];
        unsigned long long mC = __ballot(isC);
        unsigned long long mS = __ballot(isS);
        if (lane == 0) { wcntC[wv] = __popcll(mC); wcntS[wv] = __popcll(mS); }
        __syncthreads();
        const int ncn = wcntC[0] + wcntC[1] + wcntC[2] + wcntC[3];
        if (ncn == 0) break;                         // no cycles: h[] = solution
        const int n = Lc - ncn;
        {
            int baseC = 0, baseS = 0;
            for (int k = 0; k < wv; ++k) { baseC += wcntC[k]; baseS += wcntS[k]; }
            if (isC) {
                int pos = baseC + __popcll(mC & ((1ull << lane) - 1ull));
                cycnodes[pos] = (unsigned short)t;
            }
            if (isS) {
                int pos = baseS + __popcll(mS & ((1ull << lane) - 1ull));
                non_c[pos] = (unsigned short)t;
                inv_[t] = (unsigned short)pos;
            }
        }
        __syncthreads();

        // ---- thread 0: enumerate cycles (short walks over members only) ----
        if (t == 0) {
            int nc = 0, pos = 0;
            for (int q = 0; q < ncn; ++q) {
                const int s = cycnodes[q];
                if (cid[s] != 0xFF) continue;
                coff[nc] = (unsigned short)pos;
                int v = s;
                do {
                    cmem[pos] = (unsigned short)v;
                    cid[v] = (unsigned char)nc;
                    ++pos;
                    v = h[v];
                } while (v != s);
                wsl[nc] = act[s];
                ++nc;
            }
            coff[nc] = (unsigned short)pos;
            sh_ncyc = nc;
            sh_cnt = 0;
        }
        __syncthreads();
        const int ncyc = sh_ncyc;
        const int totmem = Lc - n;
        const int n_new = n + ncyc;

        // ---- member aux (reads old h/hval before overwrite) ----
        if (t < totmem) {
            chsm[t] = hval[cmem[t]];                 // = M[heads[v]][v]
            cmemhead[t] = h[cmem[t]];
        }
        __syncthreads();

        // ---- meta offsets ----
        const int o_non  = moff;
        const int o_mem  = moff + n;
        const int o_mh   = o_mem + totmem;
        const int o_aout = o_mh + totmem;
        const int o_ain  = o_aout + ncyc * Lc;
        if (t < n) mp[o_non + t] = (unsigned char)non_c[t];
        if (t < totmem) {
            mp[o_mem + t] = (unsigned char)cmem[t];
            mp[o_mh + t] = (unsigned char)cmemhead[t];
        }

        // ---- PASS 1: supernode ROWS over all old columns (coalesced) ----
        if (t < Lc) {
            const int cslot = act[t];
            for (int k = 0; k < ncyc; ++k) {
                T bo = -INFINITY; int bp = coff[k];
                for (int pos = coff[k]; pos < coff[k + 1]; ++pos) {
                    T v = M[(int)act[cmem[pos]] * Nn + cslot];
                    if (v > bo) { bo = v; bp = pos; }
                }
                M[(int)wsl[k] * Nn + cslot] = bo;
                mp[o_aout + k * Lc + t] = (unsigned char)bp;   // abs stream idx
            }
        }
        __syncthreads();

        // ---- PASS 2: supernode COLUMNS from all new sources ----
        if (t < n_new) {
            const int slot_x = (t < n) ? (int)act[non_c[t]] : (int)wsl[t - n];
            for (int k = 0; k < ncyc; ++k) {
                if (t == n + k) {
                    M[(int)wsl[k] * Nn + (int)wsl[k]] = (T)(-INFINITY);
                    continue;
                }
                T bv = -INFINITY; int bp = coff[k];
                for (int pos = coff[k]; pos < coff[k + 1]; ++pos) {
                    T v = M[slot_x * Nn + (int)act[cmem[pos]]] - chsm[pos];
                    if (v > bv) { bv = v; bp = pos; }
                }
                M[slot_x * Nn + (int)wsl[k]] = bv;
                mp[o_ain + k * n_new + t] = (unsigned char)bp; // abs stream idx
            }
        }

        // ---- capture old state (h/hval/act/inv_/cid untouched by passes) ----
        unsigned short myact = 0, myh = 0; T myhval = (T)0; bool alive = false;
        if (t < n) {
            const int oc = non_c[t];
            myact = act[oc];
            const int ho = h[oc];
            alive = (cid[ho] == 0xFF);
            if (alive) { myh = inv_[ho]; myhval = hval[oc]; }
        }
        __syncthreads();

        // ---- remap; enqueue rescans (dirty survivors + supernode cols) ----
        if (t < n) {
            act[t] = myact;
            if (alive) { h[t] = myh; hval[t] = myhval; }
            else { int kk = atomicAdd(&sh_cnt, 1); resc[kk] = (unsigned short)t; }
        }
        if (t < ncyc) {
            act[n + t] = wsl[t];
            int kk = atomicAdd(&sh_cnt, 1); resc[kk] = (unsigned short)(n + t);
        }
        if (t == 0) {
            h[0] = 0;
            lev_n[depth] = (unsigned short)n;
            lev_ncyc[depth] = (unsigned short)ncyc;
            lev_Lc[depth] = (unsigned short)Lc;
            lev_off[depth] = moff;
        }
        __syncthreads();
        moff += n + 2 * totmem + ncyc * (Lc + n_new);
        ++depth;
        Lc = n_new;

        // ---- rescan enqueued columns, 8-wide load batching ----
        const int nr = sh_cnt;
        if (t < nr) {
            const int jc = resc[t];
            const int cslot = act[jc];
            T best = -INFINITY; int bi = 0;
            int i = 0;
            for (; i + 8 <= Lc; i += 8) {
                int rows[8];
                #pragma unroll
                for (int k = 0; k < 8; ++k) rows[k] = act[i + k];
                T v[8];
                #pragma unroll
                for (int k = 0; k < 8; ++k) v[k] = M[rows[k] * Nn + cslot];
                #pragma unroll
                for (int k = 0; k < 8; ++k)
                    if (v[k] > best) { best = v[k]; bi = i + k; }
            }
            for (; i < Lc; ++i) {
                T v = M[(int)act[i] * Nn + cslot];
                if (v > best) { best = v; bi = i; }
            }
            h[jc] = (unsigned short)bi;
            hval[jc] = best;
        }
        __syncthreads();
    }

    // ---- unwind (multi-cycle expansion, reverse level order) ----
    unsigned short* hcur = h;
    unsigned short* hnew = h2;
    for (int lvl = depth - 1; lvl >= 0; --lvl) {
        const int n = lev_n[lvl];
        const int ncyc = lev_ncyc[lvl];
        const int Lco = lev_Lc[lvl];
        const int off = lev_off[lvl];
        const int totmem = Lco - n;
        const int n_new = n + ncyc;
        const int o_mem  = off + n;
        const int o_mh   = o_mem + totmem;
        const int o_aout = o_mh + totmem;
        const int o_ain  = o_aout + ncyc * Lco;
        if (t < n) {
            const int j = mp[off + t];
            const int x = hcur[t];
            hnew[j] = (x < n)
                ? (unsigned short)mp[off + x]
                : (unsigned short)mp[o_mem + mp[o_aout + (x - n) * Lco + j]];
        }
        if (t < totmem) {
            const int v = mp[o_mem + t];
            hnew[v] = (unsigned short)mp[o_mh + t];
        }
        __syncthreads();
        if (t < ncyc) {
            const int hk = hcur[n + t];
            const int ain = mp[o_ain + t * n_new + hk];
            const int vstar = mp[o_mem + ain];
            const int src = (hk < n)
                ? (int)mp[off + hk]
                : (int)mp[o_mem + mp[o_aout + (hk - n) * Lco + vstar]];
            hnew[vstar] = (unsigned short)src;
        }
        if (t == 0) hnew[0] = 0;
        __syncthreads();
        unsigned short* tmp = hcur; hcur = hnew; hnew = tmp;
    }

    // ---- emit arb (ones) and stats ----
    double acc = 0.0;
    if (t >= 1 && t < L) {
        const int hd = hcur[t];
        arb[(size_t)b * (Nn * Nn) + hd * Nn + t] = 1.0f;
        acc = (double)zb[hd * Nn + t];
    }
    red[t] = acc;
    __syncthreads();
    for (int s = 128; s > 0; s >>= 1) {
        if (t < s) red[t] += red[t + s];
        __syncthreads();
    }
    if (t == 0) stats[b] = (float)red[0];
}

// ---------------------------------------------------------------------------
extern "C" void kernel_launch(void* const* d_in, const int* in_sizes, int n_in,
                              void* d_out, int out_size, void* d_ws, size_t ws_size,
                              hipStream_t stream)
{
    const float* logits  = (const float*)d_in[0];
    const float* u       = (const float*)d_in[1];
    const int*   lengths = (const int*)d_in[2];

    float* out   = (float*)d_out;
    float* arb   = out;                                  // Bn*Nn*Nn
    float* stats = out + (size_t)Bn * Nn * Nn;           // Bn
    float* zout  = stats + Bn;                           // Bn*Nn*Nn

    const int total = Bn * Nn * Nn;
    const int zblocks = total / 256;

    const size_t needD = (size_t)Bn * Nn * Nn * sizeof(double) + (size_t)Bn * META_PB;

    if (ws_size >= needD) {
        double* M = (double*)d_ws;
        unsigned char* meta = (unsigned char*)d_ws + (size_t)Bn * Nn * Nn * sizeof(double);
        zinit_kernel<double><<<zblocks, 256, 0, stream>>>(logits, u, zout, arb, M);
        edmonds_kernel<double><<<Bn, 256, 0, stream>>>(lengths, zout, M, meta, arb, stats);
    } else {
        // fallback: f32 score matrices (tiny risk of ulp-level argmax flips)
        float* M = (float*)d_ws;
        unsigned char* meta = (unsigned char*)d_ws + (size_t)Bn * Nn * Nn * sizeof(float);
        zinit_kernel<float><<<zblocks, 256, 0, stream>>>(logits, u, zout, arb, M);
        edmonds_kernel<float><<<Bn, 256, 0, stream>>>(lengths, zout, M, meta, arb, stats);
    }
}

// Round 13
// 839.192 us; speedup vs baseline: 1.0251x; 1.0251x over previous
//
#include <hip/hip_runtime.h>
#include <cmath>

static constexpr int Bn = 128;
static constexpr int Nn = 256;
static constexpr int META_PB = 131072;   // per-batch metadata bytes (uint8)
static constexpr int PAIR_CAP = 16;      // max 2-cycles contracted per level

// ---------------------------------------------------------------------------
// Kernel 1: z = logits - log(-log(clip(u))), zero arb, init score matrix
// ---------------------------------------------------------------------------
template <typename T>
__global__ __launch_bounds__(256) void zinit_kernel(
    const float* __restrict__ logits,
    const float* __restrict__ u,
    float* __restrict__ zout,
    float* __restrict__ arb,
    T* __restrict__ M)
{
    int idx = blockIdx.x * blockDim.x + threadIdx.x;   // < Bn*Nn*Nn
    int j = idx & (Nn - 1);
    int i = (idx >> 8) & (Nn - 1);
    const float EPS = 1.1920928955078125e-07f;         // float32 eps
    float uv = u[idx];
    uv = fminf(fmaxf(uv, EPS), 1.0f - EPS);
    float z = logits[idx] - logf(-logf(uv));
    zout[idx] = z;
    arb[idx] = 0.0f;
    M[idx] = (i == j || j == 0) ? (T)(-INFINITY) : (T)z;
}

// ---------------------------------------------------------------------------
// Kernel 2: per-batch Chu-Liu/Edmonds, multi-cycle simultaneous contraction
// (R12-verified machinery) + FAST PATH: levels with mutual-argmax 2-cycles
// contract all pairs (<=16) with no pointer doubling and no serial walk.
// ---------------------------------------------------------------------------
template <typename T>
__global__ __launch_bounds__(256) void edmonds_kernel(
    const int* __restrict__ lengths,
    const float* __restrict__ zout,
    T* __restrict__ Mg,
    unsigned char* __restrict__ metag,
    float* __restrict__ arb,
    float* __restrict__ stats)
{
    const int b = blockIdx.x;
    const int t = threadIdx.x;
    const int lane = t & 63, wv = t >> 6;
    T* M = Mg + (size_t)b * (Nn * Nn);
    unsigned char* mp = metag + (size_t)b * META_PB;
    const float* zb = zout + (size_t)b * (Nn * Nn);

    __shared__ unsigned short act[256];
    __shared__ unsigned short h[256];
    __shared__ unsigned short h2[256];
    __shared__ unsigned short p1[256];
    __shared__ unsigned short p2[256];
    __shared__ unsigned short inv_[256];
    __shared__ unsigned short cycnodes[256];
    __shared__ unsigned short cmem[256];
    __shared__ unsigned short cmemhead[256];
    __shared__ unsigned short non_c[256];
    __shared__ unsigned short resc[256];
    __shared__ unsigned short coff[130];
    __shared__ unsigned short wsl[129];
    __shared__ unsigned short lev_n[256], lev_ncyc[256], lev_Lc[256];
    __shared__ int lev_off[256];
    __shared__ unsigned char in_cyc[256];
    __shared__ unsigned char cid[256];
    __shared__ T hval[256];
    __shared__ T chsm[256];
    __shared__ double red[256];
    __shared__ int wcntA[4], wcntS[4];
    __shared__ int sh_ncyc, sh_cnt, sh_pairs;

    const int L = lengths[b];

    act[t] = (unsigned short)t;
    // ---- initial full column argmax (first-max), 8-wide load batching ----
    if (t < L) {
        T best = -INFINITY; int bi = 0;
        const T* col = M + t;
        int i = 0;
        for (; i + 8 <= L; i += 8) {
            T v[8];
            #pragma unroll
            for (int k = 0; k < 8; ++k) v[k] = col[(i + k) * Nn];
            #pragma unroll
            for (int k = 0; k < 8; ++k)
                if (v[k] > best) { best = v[k]; bi = i + k; }
        }
        for (; i < L; ++i) {
            T v = col[i * Nn];
            if (v > best) { best = v; bi = i; }
        }
        h[t] = (t == 0) ? (unsigned short)0 : (unsigned short)bi;
        hval[t] = best;
    }
    __syncthreads();

    int Lc = L, depth = 0, moff = 0;

    while (true) {
        // ---- A: clear marks, seed doubling buffer ----
        in_cyc[t] = 0;
        cid[t] = 0xFF;
        if (t < Lc) p1[t] = h[t];
        __syncthreads();

        // ---- B: mutual-pair detection (no doubling needed) ----
        bool isPair = false;
        int ht = 0;
        if (t >= 1 && t < Lc) {
            ht = h[t];
            if (ht >= 1 && t < ht && h[ht] == t) isPair = true;
        }
        unsigned long long mP = __ballot(isPair);
        if (lane == 0) wcntA[wv] = __popcll(mP);
        __syncthreads();
        const int totPairs = wcntA[0] + wcntA[1] + wcntA[2] + wcntA[3];

        // ---- C: enumerate pairs (capped) OR fall through to doubling ----
        if (totPairs > 0) {
            int base = 0;
            for (int k = 0; k < wv; ++k) base += wcntA[k];
            if (isPair) {
                int pos = base + __popcll(mP & ((1ull << lane) - 1ull));
                if (pos < PAIR_CAP) {
                    in_cyc[t] = 1; in_cyc[ht] = 1;
                    cid[t] = (unsigned char)pos; cid[ht] = (unsigned char)pos;
                    cmem[2 * pos] = (unsigned short)t;
                    cmem[2 * pos + 1] = (unsigned short)ht;
                    coff[pos] = (unsigned short)(2 * pos);
                    wsl[pos] = act[t];
                }
            }
            if (t == 0) {
                const int nc = (totPairs < PAIR_CAP) ? totPairs : PAIR_CAP;
                sh_ncyc = nc;
                coff[nc] = (unsigned short)(2 * nc);
                sh_cnt = 0;
                sh_pairs = 1;
            }
            __syncthreads();
        } else {
            // ---- doubling path (R12-verified) ----
            const int rounds = 32 - __clz(Lc - 1);
            unsigned short* pa = p1;
            unsigned short* pb = p2;
            for (int r = 0; r < rounds; ++r) {
                if (t < Lc) pb[t] = pa[pa[t]];
                __syncthreads();
                unsigned short* tmp = pa; pa = pb; pb = tmp;
            }
            if (t < Lc && pa[t] != 0) in_cyc[pa[t]] = 1;
            __syncthreads();
            const bool isC = (t < Lc) && in_cyc[t];
            unsigned long long mC = __ballot(isC);
            if (lane == 0) wcntA[wv] = __popcll(mC);
            __syncthreads();
            const int ncn = wcntA[0] + wcntA[1] + wcntA[2] + wcntA[3];
            if (ncn == 0) break;                     // no cycles: h[] = solution
            {
                int baseC = 0;
                for (int k = 0; k < wv; ++k) baseC += wcntA[k];
                if (isC) {
                    int pos = baseC + __popcll(mC & ((1ull << lane) - 1ull));
                    cycnodes[pos] = (unsigned short)t;
                }
            }
            __syncthreads();
            if (t == 0) {
                int nc = 0, pos = 0;
                for (int q = 0; q < ncn; ++q) {
                    const int s = cycnodes[q];
                    if (cid[s] != 0xFF) continue;
                    coff[nc] = (unsigned short)pos;
                    int v = s;
                    do {
                        cmem[pos] = (unsigned short)v;
                        cid[v] = (unsigned char)nc;
                        ++pos;
                        v = h[v];
                    } while (v != s);
                    wsl[nc] = act[s];
                    ++nc;
                }
                coff[nc] = (unsigned short)pos;
                sh_ncyc = nc;
                sh_cnt = 0;
                sh_pairs = 0;
            }
            __syncthreads();
        }

        const int ncyc = sh_ncyc;
        const int totmem = coff[ncyc];
        const int n = Lc - totmem;
        const int n_new = n + ncyc;

        // ---- survivor compaction (from !in_cyc) ----
        const bool isS = (t < Lc) && !in_cyc[t];
        unsigned long long mS = __ballot(isS);
        if (lane == 0) wcntS[wv] = __popcll(mS);
        __syncthreads();
        if (isS) {
            int baseS = 0;
            for (int k = 0; k < wv; ++k) baseS += wcntS[k];
            int pos = baseS + __popcll(mS & ((1ull << lane) - 1ull));
            non_c[pos] = (unsigned short)t;
            inv_[t] = (unsigned short)pos;
        }
        // member aux (reads old h/hval)
        if (t < totmem) {
            chsm[t] = hval[cmem[t]];
            cmemhead[t] = h[cmem[t]];
        }
        __syncthreads();

        // ---- meta offsets ----
        const int o_non  = moff;
        const int o_mem  = moff + n;
        const int o_mh   = o_mem + totmem;
        const int o_aout = o_mh + totmem;
        const int o_ain  = o_aout + ncyc * Lc;
        if (t < n) mp[o_non + t] = (unsigned char)non_c[t];
        if (t < totmem) {
            mp[o_mem + t] = (unsigned char)cmem[t];
            mp[o_mh + t] = (unsigned char)cmemhead[t];
        }

        // ---- PASS 1: supernode ROWS over all old columns (coalesced) ----
        if (t < Lc) {
            const int cslot = act[t];
            for (int k = 0; k < ncyc; ++k) {
                T bo = -INFINITY; int bp = coff[k];
                for (int pos = coff[k]; pos < coff[k + 1]; ++pos) {
                    T v = M[(int)act[cmem[pos]] * Nn + cslot];
                    if (v > bo) { bo = v; bp = pos; }
                }
                M[(int)wsl[k] * Nn + cslot] = bo;
                mp[o_aout + k * Lc + t] = (unsigned char)bp;
            }
        }
        __syncthreads();

        // ---- PASS 2: supernode COLUMNS from all new sources ----
        if (t < n_new) {
            const int slot_x = (t < n) ? (int)act[non_c[t]] : (int)wsl[t - n];
            for (int k = 0; k < ncyc; ++k) {
                if (t == n + k) {
                    M[(int)wsl[k] * Nn + (int)wsl[k]] = (T)(-INFINITY);
                    continue;
                }
                T bv = -INFINITY; int bp = coff[k];
                for (int pos = coff[k]; pos < coff[k + 1]; ++pos) {
                    T v = M[slot_x * Nn + (int)act[cmem[pos]]] - chsm[pos];
                    if (v > bv) { bv = v; bp = pos; }
                }
                M[slot_x * Nn + (int)wsl[k]] = bv;
                mp[o_ain + k * n_new + t] = (unsigned char)bp;
            }
        }

        // ---- capture old state ----
        unsigned short myact = 0, myh = 0; T myhval = (T)0; bool alive = false;
        if (t < n) {
            const int oc = non_c[t];
            myact = act[oc];
            const int ho = h[oc];
            alive = (cid[ho] == 0xFF);
            if (alive) { myh = inv_[ho]; myhval = hval[oc]; }
        }
        __syncthreads();

        // ---- remap; enqueue rescans ----
        if (t < n) {
            act[t] = myact;
            if (alive) { h[t] = myh; hval[t] = myhval; }
            else { int kk = atomicAdd(&sh_cnt, 1); resc[kk] = (unsigned short)t; }
        }
        if (t < ncyc) {
            act[n + t] = wsl[t];
            int kk = atomicAdd(&sh_cnt, 1); resc[kk] = (unsigned short)(n + t);
        }
        if (t == 0) {
            h[0] = 0;
            lev_n[depth] = (unsigned short)n;
            lev_ncyc[depth] = (unsigned short)ncyc;
            lev_Lc[depth] = (unsigned short)Lc;
            lev_off[depth] = moff;
        }
        __syncthreads();
        moff += n + 2 * totmem + ncyc * (Lc + n_new);
        ++depth;
        Lc = n_new;

        // ---- rescan enqueued columns, 8-wide load batching ----
        const int nr = sh_cnt;
        if (t < nr) {
            const int jc = resc[t];
            const int cslot = act[jc];
            T best = -INFINITY; int bi = 0;
            int i = 0;
            for (; i + 8 <= Lc; i += 8) {
                int rows[8];
                #pragma unroll
                for (int k = 0; k < 8; ++k) rows[k] = act[i + k];
                T v[8];
                #pragma unroll
                for (int k = 0; k < 8; ++k) v[k] = M[rows[k] * Nn + cslot];
                #pragma unroll
                for (int k = 0; k < 8; ++k)
                    if (v[k] > best) { best = v[k]; bi = i + k; }
            }
            for (; i < Lc; ++i) {
                T v = M[(int)act[i] * Nn + cslot];
                if (v > best) { best = v; bi = i; }
            }
            h[jc] = (unsigned short)bi;
            hval[jc] = best;
        }
        __syncthreads();
    }

    // ---- unwind (multi-cycle expansion, reverse level order) ----
    unsigned short* hcur = h;
    unsigned short* hnew = h2;
    for (int lvl = depth - 1; lvl >= 0; --lvl) {
        const int n = lev_n[lvl];
        const int ncyc = lev_ncyc[lvl];
        const int Lco = lev_Lc[lvl];
        const int off = lev_off[lvl];
        const int totmem = Lco - n;
        const int n_new = n + ncyc;
        const int o_mem  = off + n;
        const int o_mh   = o_mem + totmem;
        const int o_aout = o_mh + totmem;
        const int o_ain  = o_aout + ncyc * Lco;
        if (t < n) {
            const int j = mp[off + t];
            const int x = hcur[t];
            hnew[j] = (x < n)
                ? (unsigned short)mp[off + x]
                : (unsigned short)mp[o_mem + mp[o_aout + (x - n) * Lco + j]];
        }
        if (t < totmem) {
            const int v = mp[o_mem + t];
            hnew[v] = (unsigned short)mp[o_mh + t];
        }
        __syncthreads();
        if (t < ncyc) {
            const int hk = hcur[n + t];
            const int ain = mp[o_ain + t * n_new + hk];
            const int vstar = mp[o_mem + ain];
            const int src = (hk < n)
                ? (int)mp[off + hk]
                : (int)mp[o_mem + mp[o_aout + (hk - n) * Lco + vstar]];
            hnew[vstar] = (unsigned short)src;
        }
        if (t == 0) hnew[0] = 0;
        __syncthreads();
        unsigned short* tmp = hcur; hcur = hnew; hnew = tmp;
    }

    // ---- emit arb (ones) and stats ----
    double acc = 0.0;
    if (t >= 1 && t < L) {
        const int hd = hcur[t];
        arb[(size_t)b * (Nn * Nn) + hd * Nn + t] = 1.0f;
        acc = (double)zb[hd * Nn + t];
    }
    red[t] = acc;
    __syncthreads();
    for (int s = 128; s > 0; s >>= 1) {
        if (t < s) red[t] += red[t + s];
        __syncthreads();
    }
    if (t == 0) stats[b] = (float)red[0];
}

// ---------------------------------------------------------------------------
extern "C" void kernel_launch(void* const* d_in, const int* in_sizes, int n_in,
                              void* d_out, int out_size, void* d_ws, size_t ws_size,
                              hipStream_t stream)
{
    const float* logits  = (const float*)d_in[0];
    const float* u       = (const float*)d_in[1];
    const int*   lengths = (const int*)d_in[2];

    float* out   = (float*)d_out;
    float* arb   = out;                                  // Bn*Nn*Nn
    float* stats = out + (size_t)Bn * Nn * Nn;           // Bn
    float* zout  = stats + Bn;                           // Bn*Nn*Nn

    const int total = Bn * Nn * Nn;
    const int zblocks = total / 256;

    const size_t needD = (size_t)Bn * Nn * Nn * sizeof(double) + (size_t)Bn * META_PB;

    if (ws_size >= needD) {
        double* M = (double*)d_ws;
        unsigned char* meta = (unsigned char*)d_ws + (size_t)Bn * Nn * Nn * sizeof(double);
        zinit_kernel<double><<<zblocks, 256, 0, stream>>>(logits, u, zout, arb, M);
        edmonds_kernel<double><<<Bn, 256, 0, stream>>>(lengths, zout, M, meta, arb, stats);
    } else {
        // fallback: f32 score matrices (tiny risk of ulp-level argmax flips)
        float* M = (float*)d_ws;
        unsigned char* meta = (unsigned char*)d_ws + (size_t)Bn * Nn * Nn * sizeof(float);
        zinit_kernel<float><<<zblocks, 256, 0, stream>>>(logits, u, zout, arb, M);
        edmonds_kernel<float><<<Bn, 256, 0, stream>>>(lengths, zout, M, meta, arb, stats);
    }
}